// Round 6
// baseline (310.121 us; speedup 1.0000x reference)
//
#include <hip/hip_runtime.h>

#define B_  4
#define N_  4096   // H*W
#define C_  256
#define D_  32

typedef __attribute__((ext_vector_type(8))) short bf8;    // 8 bf16 (4 VGPRs)
typedef __attribute__((ext_vector_type(4))) float f4;     // 16x16 MFMA C/D frag
typedef __attribute__((ext_vector_type(16))) float f16v;  // 32x32 MFMA C/D frag

__device__ __forceinline__ unsigned short bft(float f) {
    unsigned u = __builtin_bit_cast(unsigned, f);
    return (unsigned short)((u + 0x8000u) >> 16);
}
// pack two floats to bf16x2 (a->low, b->high), round-half-up, 3 VALU ops
__device__ __forceinline__ unsigned pk2(float a, float b) {
    unsigned ua = __builtin_bit_cast(unsigned, a) + 0x8000u;
    unsigned ub = __builtin_bit_cast(unsigned, b) + 0x8000u;
    return __builtin_amdgcn_perm(ub, ua, 0x07060302u);  // bytes {b3,b2,a3,a2}
}

// ---------------------------------------------------------------------------
// prep: weights -> bf16. Wqkb[64][256] = Wq rows 0-31, Wk rows 32-63.
// ---------------------------------------------------------------------------
__global__ __launch_bounds__(256) void prep(
    const float* __restrict__ Wq, const float* __restrict__ Wk,
    const float* __restrict__ Wv,
    unsigned short* __restrict__ Wqkb, unsigned short* __restrict__ Wvb)
{
    int i = blockIdx.x * 256 + threadIdx.x;
    if (i < 8192)       Wqkb[i] = bft(Wq[i]);
    else if (i < 16384) Wqkb[i] = bft(Wk[i - 8192]);
    Wvb[i] = bft(Wv[i]);
}

// ---------------------------------------------------------------------------
// qkv: MFMA projections, coalesced staging. grid(128,4), 256 thr.
// q is pre-scaled by log2(e) so attn can use raw v_exp_f32 (2^x).
// Outputs: qb,kb [B][N][32] bf16 ; vb [B][C][N] bf16.
// ---------------------------------------------------------------------------
__global__ __launch_bounds__(256) void qkv(
    const float* __restrict__ x,
    const unsigned short* __restrict__ Wqkb, const unsigned short* __restrict__ Wvb,
    const float* __restrict__ bq, const float* __restrict__ bk,
    const float* __restrict__ bv,
    unsigned short* __restrict__ qb, unsigned short* __restrict__ kb,
    unsigned short* __restrict__ vb)
{
    const int b = blockIdx.y, n0 = blockIdx.x * 32;
    const int t = threadIdx.x;
    const int lane = t & 63, w = t >> 6, c15 = lane & 15, g = lane >> 4;

    __shared__ __align__(16) unsigned short xs[32][264];

    // coalesced stage + transpose: 8 lanes cover one 128-B row segment
    {
        const int r = t >> 3, cg = t & 7;
        #pragma unroll
        for (int it = 0; it < 8; ++it) {
            int c = r + 32 * it;
            float4 v = *(const float4*)(x + ((size_t)(b * C_ + c)) * N_ + n0 + cg * 4);
            xs[cg * 4 + 0][c] = bft(v.x);
            xs[cg * 4 + 1][c] = bft(v.y);
            xs[cg * 4 + 2][c] = bft(v.z);
            xs[cg * 4 + 3][c] = bft(v.w);
        }
    }
    __syncthreads();

    f4 qkacc[2]; f4 vacc[2][4];
    const f4 fz = {0.f, 0.f, 0.f, 0.f};
    qkacc[0] = fz; qkacc[1] = fz;
    #pragma unroll
    for (int nt = 0; nt < 2; ++nt)
        #pragma unroll
        for (int ct = 0; ct < 4; ++ct) vacc[nt][ct] = fz;

    const unsigned short* wqk = Wqkb + (w * 16 + c15) * C_ + g * 8;
    const unsigned short* wv0 = Wvb + (w * 64 + c15) * C_ + g * 8;
    const unsigned short* xsp = &xs[c15][g * 8];

    #pragma unroll
    for (int ks = 0; ks < 8; ++ks) {
        bf8 xf0 = *(const bf8*)(xsp + ks * 32);
        bf8 xf1 = *(const bf8*)(xsp + 16 * 264 + ks * 32);
        bf8 af  = *(const bf8*)(wqk + ks * 32);
        qkacc[0] = __builtin_amdgcn_mfma_f32_16x16x32_bf16(af, xf0, qkacc[0], 0, 0, 0);
        qkacc[1] = __builtin_amdgcn_mfma_f32_16x16x32_bf16(af, xf1, qkacc[1], 0, 0, 0);
        #pragma unroll
        for (int ct = 0; ct < 4; ++ct) {
            bf8 bfv = *(const bf8*)(wv0 + ct * 16 * C_ + ks * 32);
            vacc[0][ct] = __builtin_amdgcn_mfma_f32_16x16x32_bf16(xf0, bfv, vacc[0][ct], 0, 0, 0);
            vacc[1][ct] = __builtin_amdgcn_mfma_f32_16x16x32_bf16(xf1, bfv, vacc[1][ct], 0, 0, 0);
        }
    }

    // epilogue q/k (q scaled by log2e for exp2-softmax)
    {
        float4 bias = (w < 2) ? *(const float4*)(bq + (w & 1) * 16 + 4 * g)
                              : *(const float4*)(bk + (w & 1) * 16 + 4 * g);
        float sc = (w < 2) ? 1.44269504f : 1.0f;
        unsigned short* base = (w < 2) ? qb : kb;
        int d0 = (w & 1) * 16 + 4 * g;
        #pragma unroll
        for (int nt = 0; nt < 2; ++nt) {
            int n = n0 + nt * 16 + c15;
            f4 a = qkacc[nt];
            uint2 pk;
            pk.x = pk2((a.x + bias.x) * sc, (a.y + bias.y) * sc);
            pk.y = pk2((a.z + bias.z) * sc, (a.w + bias.w) * sc);
            *(uint2*)(base + ((size_t)(b * N_ + n)) * D_ + d0) = pk;
        }
    }
    // epilogue v
    #pragma unroll
    for (int ct = 0; ct < 4; ++ct) {
        int cout = w * 64 + ct * 16 + c15;
        float bvv = bv[cout];
        #pragma unroll
        for (int nt = 0; nt < 2; ++nt) {
            f4 a = vacc[nt][ct];
            uint2 pk;
            pk.x = pk2(a.x + bvv, a.y + bvv);
            pk.y = pk2(a.z + bvv, a.w + bvv);
            *(uint2*)(vb + ((size_t)(b * C_ + cout)) * (size_t)N_ + n0 + nt * 16 + 4 * g) = pk;
        }
    }
}

// ---------------------------------------------------------------------------
// attn v7 (= v6 with the P-buffer layout bug fixed): barrier-free main loop,
// wave-private LDS P round-trip.
// Wave = (b, 32 m-rows, 128 c-half, 1024 n-quarter). Block = the 4 n-quarter
// waves of one (b,m,c-half); grid 1024 = 4b x 2ch x 128mb, bid&7 = (b,ch)
// pins each XCD's L2 to its 1MB V-slice. 32x32x16 MFMAs throughout.
// P buffer: 32 rows x 80-byte stride (64B data + 16B pad), NO xor swizzle.
//   v6's XOR put bit-6 (=64) into the offset -> crossed the 64-B row and
//   collided (cl=15 vs cl=16) / overflowed the wave buffer (cl=31) -> NaN.
//   With 80-B stride (20 banks): b128 reads = start banks {0,4..28} x8 lanes
//   = 8 words/bank uniform (the b128 floor); b64 writes = even start banks
//   x4 lanes = 4 words/bank uniform (floor). Zero extra conflict cycles.
// Per 32-n iter (NO barrier, NO cross-wave dep):
//   QK: S^T = K.Q^T (2 MFMA, D=32) -> exp2 x16, pack, write private P ->
//   read back 2x b128 as PV A-frags -> PV: 8 MFMA into acc[4] (32m x 128c).
//   K reg-double-buffered; V (8x b128) issued at iter top, used at the end.
// 12 waves/CU (launch_bounds 256,3) drift freely -> MFMA/trans/VALU/LDS mix
// across waves; the v2..v5 barrier convoy is gone.
// One-time epilogue: ds_add_f32 into Osum[c][m^cl] (bank-uniform 2-way,
// free), l via ds_add, one __syncthreads, normalize + x-add, coalesced out.
// ---------------------------------------------------------------------------
__global__ __launch_bounds__(256, 3) void attn(
    const unsigned short* __restrict__ qb, const unsigned short* __restrict__ kb,
    const unsigned short* __restrict__ vb, const float* __restrict__ x,
    const float* __restrict__ gamma, float* __restrict__ out)
{
    const int bid = blockIdx.x;
    const int combo = bid & 7, mb = bid >> 3;
    const int b = combo >> 1, c0 = (combo & 1) * 128, m0 = mb * 32;
    const int t = threadIdx.x;
    const int lane = t & 63, w = t >> 6;
    const int cl = lane & 31, h = lane >> 5;

    __shared__ __align__(16) char Pbuf[4][32 * 80];          // 10KB: 2.5KB/wave, 80-B rows
    __shared__ __align__(16) float Osum[128][32];            // [c][m^cl] 16KB
    __shared__ float l_tot[32];

    // zero accumulators (one-time)
    for (int i = t; i < 128 * 32; i += 256) (&Osum[0][0])[i] = 0.f;
    if (t < 32) l_tot[t] = 0.f;
    __syncthreads();

    char* pb = &Pbuf[w][0];

    // Q frags (B-operand, col=m=cl, k=d): hoisted
    bf8 qf[2];
    #pragma unroll
    for (int kh = 0; kh < 2; ++kh)
        qf[kh] = *(const bf8*)(qb + ((size_t)(b * N_) + m0 + cl) * D_ + kh * 16 + 8 * h);

    f16v acc[4];   // [c-tile]: 32m x 128c, 64 VGPR
    #pragma unroll
    for (int ct = 0; ct < 4; ++ct) acc[ct] = (f16v)0.f;
    float lr = 0.f;

    const unsigned short* kB = kb + ((size_t)(b * N_) + w * 1024) * D_;
    const unsigned short* vB = vb + ((size_t)(b * C_ + c0)) * (size_t)N_ + w * 1024;

    // K register double-buffer (A-operand, row=n=cl, k=d)
    bf8 kfc[2], kfn[2];
    #pragma unroll
    for (int kh = 0; kh < 2; ++kh)
        kfc[kh] = *(const bf8*)(kB + (size_t)cl * D_ + kh * 16 + 8 * h);

    for (int it = 0; it < 1024; it += 32) {
        // V loads (B-operand frags, col=c, k=n): issued first, used last
        bf8 vf[2][4];
        #pragma unroll
        for (int kh = 0; kh < 2; ++kh)
            #pragma unroll
            for (int ct = 0; ct < 4; ++ct)
                vf[kh][ct] = *(const bf8*)(vB + (size_t)(ct * 32 + cl) * N_
                                           + it + kh * 16 + 8 * h);
        // next-iter K prefetch
        {
            const int itn = (it < 992) ? it + 32 : it;
            #pragma unroll
            for (int kh = 0; kh < 2; ++kh)
                kfn[kh] = *(const bf8*)(kB + (size_t)(itn + cl) * D_ + kh * 16 + 8 * h);
        }
        // QK: S^T[n][m] over D=32 (2 chained MFMA)
        f16v s = __builtin_amdgcn_mfma_f32_32x32x16_bf16(kfc[0], qf[0], (f16v)0.f, 0, 0, 0);
        s = __builtin_amdgcn_mfma_f32_32x32x16_bf16(kfc[1], qf[1], s, 0, 0, 0);
        kfc[0] = kfn[0]; kfc[1] = kfn[1];
        // exp2 (q pre-scaled by log2e), pack, private-P write
        // lane col m=cl; reg r -> n=(r&3)+8*(r>>2)+4h; q-group writes n=8q+4h+0..3
        #pragma unroll
        for (int q = 0; q < 4; ++q) {
            float p0 = __builtin_amdgcn_exp2f(s[4 * q + 0]);
            float p1 = __builtin_amdgcn_exp2f(s[4 * q + 1]);
            float p2 = __builtin_amdgcn_exp2f(s[4 * q + 2]);
            float p3 = __builtin_amdgcn_exp2f(s[4 * q + 3]);
            lr += (p0 + p1) + (p2 + p3);
            uint2 pk; pk.x = pk2(p0, p1); pk.y = pk2(p2, p3);
            *(uint2*)(pb + cl * 80 + 16 * q + 8 * h) = pk;
        }
        // read P back as PV A-frags (row=m=cl, k=n-chunk) and accumulate O
        #pragma unroll
        for (int kh = 0; kh < 2; ++kh) {
            bf8 pf = *(const bf8*)(pb + cl * 80 + 32 * kh + 16 * h);
            #pragma unroll
            for (int ct = 0; ct < 4; ++ct)
                acc[ct] = __builtin_amdgcn_mfma_f32_32x32x16_bf16(pf, vf[kh][ct], acc[ct], 0, 0, 0);
        }
    }

    // one-time combine across the 4 n-quarter waves (LDS float atomics)
    atomicAdd(&l_tot[cl], lr);
    #pragma unroll
    for (int ct = 0; ct < 4; ++ct)
        #pragma unroll
        for (int r = 0; r < 16; ++r) {
            int m = (r & 3) + 8 * (r >> 2) + 4 * h;
            atomicAdd(&Osum[ct * 32 + cl][m ^ cl], acc[ct][r]);
        }
    __syncthreads();

    // finalize: wave w owns c-rows w*32..+31; lane: c = w*32 + (lane>>1),
    // m-halves by lane&1. Coalesced 64B-per-lane float4 stores along m.
    {
        const float g0 = gamma[0];
        const int c = w * 32 + (lane >> 1);
        const int mb2 = (lane & 1) * 16;
        float vals[16];
        #pragma unroll
        for (int i = 0; i < 16; ++i) {
            int m = mb2 + i;
            vals[i] = g0 * (Osum[c][m ^ (c & 31)] / l_tot[m]);
        }
        size_t base = ((size_t)(b * C_ + c0 + c)) * (size_t)N_ + m0 + mb2;
        #pragma unroll
        for (int i4 = 0; i4 < 4; ++i4) {
            float4 xv = *(const float4*)(x + base + 4 * i4);
            float4 r;
            r.x = vals[4 * i4 + 0] + xv.x;
            r.y = vals[4 * i4 + 1] + xv.y;
            r.z = vals[4 * i4 + 2] + xv.z;
            r.w = vals[4 * i4 + 3] + xv.w;
            *(float4*)(out + base + 4 * i4) = r;
        }
    }
}

extern "C" void kernel_launch(void* const* d_in, const int* in_sizes, int n_in,
                              void* d_out, int out_size, void* d_ws, size_t ws_size,
                              hipStream_t stream) {
    const float* x     = (const float*)d_in[0];
    const float* Wq    = (const float*)d_in[1];
    const float* bq    = (const float*)d_in[2];
    const float* Wk    = (const float*)d_in[3];
    const float* bk    = (const float*)d_in[4];
    const float* Wv    = (const float*)d_in[5];
    const float* bv    = (const float*)d_in[6];
    const float* gamma = (const float*)d_in[7];
    float* out = (float*)d_out;

    unsigned short* qb   = (unsigned short*)d_ws;
    unsigned short* kb   = qb + (size_t)B_ * N_ * D_;
    unsigned short* vb   = kb + (size_t)B_ * N_ * D_;
    unsigned short* Wqkb = vb + (size_t)B_ * C_ * N_;
    unsigned short* Wvb  = Wqkb + 64 * C_;

    prep<<<256, 256, 0, stream>>>(Wq, Wk, Wv, Wqkb, Wvb);
    qkv<<<dim3(128, 4), 256, 0, stream>>>(x, Wqkb, Wvb, bq, bk, bv, qb, kb, vb);
    attn<<<dim3(1024), 256, 0, stream>>>(qb, kb, vb, x, gamma, out);
}

// Round 7
// 239.140 us; speedup vs baseline: 1.2968x; 1.2968x over previous
//
#include <hip/hip_runtime.h>

#define B_  4
#define N_  4096   // H*W
#define C_  256
#define D_  32

typedef __attribute__((ext_vector_type(8))) short bf8;   // 8 bf16 (4 VGPRs)
typedef __attribute__((ext_vector_type(4))) float f4;    // MFMA C/D frag

__device__ __forceinline__ unsigned short bft(float f) {
    unsigned u = __builtin_bit_cast(unsigned, f);
    return (unsigned short)((u + 0x8000u) >> 16);
}
// pack two floats to bf16x2 (a->low, b->high), round-half-up, 3 VALU ops
__device__ __forceinline__ unsigned pk2(float a, float b) {
    unsigned ua = __builtin_bit_cast(unsigned, a) + 0x8000u;
    unsigned ub = __builtin_bit_cast(unsigned, b) + 0x8000u;
    return __builtin_amdgcn_perm(ub, ua, 0x07060302u);  // bytes {b3,b2,a3,a2}
}

// ---------------------------------------------------------------------------
// prep: weights -> bf16. Wqkb[64][256] = Wq rows 0-31, Wk rows 32-63.
// ---------------------------------------------------------------------------
__global__ __launch_bounds__(256) void prep(
    const float* __restrict__ Wq, const float* __restrict__ Wk,
    const float* __restrict__ Wv,
    unsigned short* __restrict__ Wqkb, unsigned short* __restrict__ Wvb)
{
    int i = blockIdx.x * 256 + threadIdx.x;
    if (i < 8192)       Wqkb[i] = bft(Wq[i]);
    else if (i < 16384) Wqkb[i] = bft(Wk[i - 8192]);
    Wvb[i] = bft(Wv[i]);
}

// ---------------------------------------------------------------------------
// qkv: MFMA projections, coalesced staging. grid(128,4), 256 thr.
// q is pre-scaled by log2(e) so attn can use raw v_exp_f32 (2^x).
// Outputs: qb,kb [B][N][32] bf16 ; vb [B][C][N] bf16.
// ---------------------------------------------------------------------------
__global__ __launch_bounds__(256) void qkv(
    const float* __restrict__ x,
    const unsigned short* __restrict__ Wqkb, const unsigned short* __restrict__ Wvb,
    const float* __restrict__ bq, const float* __restrict__ bk,
    const float* __restrict__ bv,
    unsigned short* __restrict__ qb, unsigned short* __restrict__ kb,
    unsigned short* __restrict__ vb)
{
    const int b = blockIdx.y, n0 = blockIdx.x * 32;
    const int t = threadIdx.x;
    const int lane = t & 63, w = t >> 6, c15 = lane & 15, g = lane >> 4;

    __shared__ __align__(16) unsigned short xs[32][264];

    // coalesced stage + transpose: 8 lanes cover one 128-B row segment
    {
        const int r = t >> 3, cg = t & 7;
        #pragma unroll
        for (int it = 0; it < 8; ++it) {
            int c = r + 32 * it;
            float4 v = *(const float4*)(x + ((size_t)(b * C_ + c)) * N_ + n0 + cg * 4);
            xs[cg * 4 + 0][c] = bft(v.x);
            xs[cg * 4 + 1][c] = bft(v.y);
            xs[cg * 4 + 2][c] = bft(v.z);
            xs[cg * 4 + 3][c] = bft(v.w);
        }
    }
    __syncthreads();

    f4 qkacc[2]; f4 vacc[2][4];
    const f4 fz = {0.f, 0.f, 0.f, 0.f};
    qkacc[0] = fz; qkacc[1] = fz;
    #pragma unroll
    for (int nt = 0; nt < 2; ++nt)
        #pragma unroll
        for (int ct = 0; ct < 4; ++ct) vacc[nt][ct] = fz;

    const unsigned short* wqk = Wqkb + (w * 16 + c15) * C_ + g * 8;
    const unsigned short* wv0 = Wvb + (w * 64 + c15) * C_ + g * 8;
    const unsigned short* xsp = &xs[c15][g * 8];

    #pragma unroll
    for (int ks = 0; ks < 8; ++ks) {
        bf8 xf0 = *(const bf8*)(xsp + ks * 32);
        bf8 xf1 = *(const bf8*)(xsp + 16 * 264 + ks * 32);
        bf8 af  = *(const bf8*)(wqk + ks * 32);
        qkacc[0] = __builtin_amdgcn_mfma_f32_16x16x32_bf16(af, xf0, qkacc[0], 0, 0, 0);
        qkacc[1] = __builtin_amdgcn_mfma_f32_16x16x32_bf16(af, xf1, qkacc[1], 0, 0, 0);
        #pragma unroll
        for (int ct = 0; ct < 4; ++ct) {
            bf8 bfv = *(const bf8*)(wv0 + ct * 16 * C_ + ks * 32);
            vacc[0][ct] = __builtin_amdgcn_mfma_f32_16x16x32_bf16(xf0, bfv, vacc[0][ct], 0, 0, 0);
            vacc[1][ct] = __builtin_amdgcn_mfma_f32_16x16x32_bf16(xf1, bfv, vacc[1][ct], 0, 0, 0);
        }
    }

    // epilogue q/k (q scaled by log2e for exp2-softmax)
    {
        float4 bias = (w < 2) ? *(const float4*)(bq + (w & 1) * 16 + 4 * g)
                              : *(const float4*)(bk + (w & 1) * 16 + 4 * g);
        float sc = (w < 2) ? 1.44269504f : 1.0f;
        unsigned short* base = (w < 2) ? qb : kb;
        int d0 = (w & 1) * 16 + 4 * g;
        #pragma unroll
        for (int nt = 0; nt < 2; ++nt) {
            int n = n0 + nt * 16 + c15;
            f4 a = qkacc[nt];
            uint2 pk;
            pk.x = pk2((a.x + bias.x) * sc, (a.y + bias.y) * sc);
            pk.y = pk2((a.z + bias.z) * sc, (a.w + bias.w) * sc);
            *(uint2*)(base + ((size_t)(b * N_ + n)) * D_ + d0) = pk;
        }
    }
    // epilogue v
    #pragma unroll
    for (int ct = 0; ct < 4; ++ct) {
        int cout = w * 64 + ct * 16 + c15;
        float bvv = bv[cout];
        #pragma unroll
        for (int nt = 0; nt < 2; ++nt) {
            f4 a = vacc[nt][ct];
            uint2 pk;
            pk.x = pk2(a.x + bvv, a.y + bvv);
            pk.y = pk2(a.z + bvv, a.w + bvv);
            *(uint2*)(vb + ((size_t)(b * C_ + cout)) * (size_t)N_ + n0 + nt * 16 + 4 * g) = pk;
        }
    }
}

// ---------------------------------------------------------------------------
// attn v8: v5 skeleton (M=64, c-half, 8 waves, grid 512, 2 blocks/CU,
// 272-B-row P in LDS, light lgkmcnt barrier) with PRODUCER/CONSUMER WAVE
// SPECIALIZATION: region i splits the 8 waves into two 4-wave groups,
//   consume-group ((grp^i)&1==1): tile i -> 16 P b128 reads + 32 PV MFMA
//       (s_setprio(1) around the cluster: T5 pays when roles are split)
//   produce-group: tile i+1 -> 8 QK MFMA + exp2/pack + 8 b64 P writes.
// Produce-VALU and consume-MFMA now overlap WITHIN every region instead of
// alternating as lockstep phases (v2..v5: sum-of-pipes == wall).
// Roles swap each region; each wave's acc covers its parity of tiles; the
// two groups merge through the existing v5 ksh-combine (grp == ksh role).
// Prefetch discipline: K for tile i+2 issued during consume(i); V ks{0,1}
// for tile j issued during produce(j); V ks{2,3} at consume top -- every
// global load has >= one region of latency cover, all buffers singly named
// (no runtime-indexed register arrays). vmcnt never drained at the barrier.
// P LDS layout [64][136] shorts: b128 reads land on 8 uniform bank-slots
// (floor), b64 writes 4 words/bank (floor) -- the 4-6M conflict counts of
// v1/v5 are the benign 2-lane/bank aliasing, not a cost (m136).
// ---------------------------------------------------------------------------
__global__ __launch_bounds__(512, 4) void attn(
    const unsigned short* __restrict__ qb, const unsigned short* __restrict__ kb,
    const unsigned short* __restrict__ vb, const float* __restrict__ x,
    const float* __restrict__ gamma, float* __restrict__ out)
{
    const int bid = blockIdx.x;
    const int combo = bid & 7, mb = bid >> 3;
    const int b = combo >> 1, c0 = (combo & 1) * 128, m0 = mb * 64;
    const int t = threadIdx.x;
    const int lane = t & 63, w = t >> 6, c15 = lane & 15, g = lane >> 4;
    const int u = w & 3, grp = w >> 2;           // role sub-id / group

    __shared__ __align__(16) unsigned short Ps[2][64][136];  // 272-B rows
    __shared__ float l_s[8][64];
    __shared__ __align__(16) float l_tot[64];

    const f4 fz = {0.f, 0.f, 0.f, 0.f};

    bf8 qf[4];
    #pragma unroll
    for (int mi = 0; mi < 4; ++mi)
        qf[mi] = *(const bf8*)(qb + ((size_t)(b * N_ + m0 + mi * 16 + c15)) * D_ + g * 8);

    f4 acc[4][2];
    #pragma unroll
    for (int mt = 0; mt < 4; ++mt)
        #pragma unroll
        for (int ct = 0; ct < 2; ++ct) acc[mt][ct] = fz;
    float lr[4] = {0.f, 0.f, 0.f, 0.f};

    const unsigned short* kB = kb + (size_t)b * N_ * D_;
    const unsigned short* vB = vb + ((size_t)(b * C_ + c0 + u * 32)) * (size_t)N_;

    bf8 kfc[2];      // K frags for my next produce tile (loaded in prior region)
    bf8 vfp[2][2];   // V frags ks{0,1} for my next consume tile

    // ---------------- prologue ----------------
    if (grp == 0) {
        // my region-0 role: produce tile 1
        #pragma unroll
        for (int nf = 0; nf < 2; ++nf)
            kfc[nf] = *(const bf8*)(kB + (size_t)(128 + (2 * u + nf) * 16 + c15) * D_ + g * 8);
    } else {
        // my region-0 role: consume tile 0
        #pragma unroll
        for (int ks = 0; ks < 2; ++ks)
            #pragma unroll
            for (int ct = 0; ct < 2; ++ct)
                vfp[ks][ct] = *(const bf8*)(vB + (size_t)(ct * 16 + c15) * N_ + ks * 32 + g * 8);
    }
    // all 8 waves co-produce tile 0 (wave w -> n-frag w), v5-style
    {
        bf8 kf0 = *(const bf8*)(kB + (size_t)(w * 16 + c15) * D_ + g * 8);
        #pragma unroll
        for (int mi = 0; mi < 4; ++mi) {
            f4 s = __builtin_amdgcn_mfma_f32_16x16x32_bf16(kf0, qf[mi], fz, 0, 0, 0);
            float p0 = __builtin_amdgcn_exp2f(s.x);
            float p1 = __builtin_amdgcn_exp2f(s.y);
            float p2 = __builtin_amdgcn_exp2f(s.z);
            float p3 = __builtin_amdgcn_exp2f(s.w);
            lr[mi] += (p0 + p1) + (p2 + p3);
            uint2 pk; pk.x = pk2(p0, p1); pk.y = pk2(p2, p3);
            *(uint2*)&Ps[0][mi * 16 + c15][w * 16 + 4 * g] = pk;
        }
    }
    asm volatile("s_waitcnt lgkmcnt(0)\n\ts_barrier" ::: "memory");

    // ---------------- main: 32 regions, alternating roles ----------------
    for (int i = 0; i < 32; ++i) {
        if (((grp ^ i) & 1) != 0) {
            // ================= CONSUME tile i =================
            // K prefetch for my produce next region (tile i+2)
            if (i + 2 < 32) {
                #pragma unroll
                for (int nf = 0; nf < 2; ++nf)
                    kfc[nf] = *(const bf8*)(kB + (size_t)((i + 2) * 128 + (2 * u + nf) * 16 + c15) * D_ + g * 8);
            }
            // V second half (ks 2,3) of this tile
            bf8 vfl[2][2];
            #pragma unroll
            for (int ks = 0; ks < 2; ++ks)
                #pragma unroll
                for (int ct = 0; ct < 2; ++ct)
                    vfl[ks][ct] = *(const bf8*)(vB + (size_t)(ct * 16 + c15) * N_
                                                + i * 128 + (ks + 2) * 32 + g * 8);
            const unsigned short (*pbR)[136] = Ps[i & 1];
            __builtin_amdgcn_s_setprio(1);
            #pragma unroll
            for (int ks = 0; ks < 2; ++ks) {
                bf8 pf[4];
                #pragma unroll
                for (int mt = 0; mt < 4; ++mt)
                    pf[mt] = *(const bf8*)&pbR[mt * 16 + c15][ks * 32 + 8 * g];
                #pragma unroll
                for (int mt = 0; mt < 4; ++mt) {
                    acc[mt][0] = __builtin_amdgcn_mfma_f32_16x16x32_bf16(pf[mt], vfp[ks][0], acc[mt][0], 0, 0, 0);
                    acc[mt][1] = __builtin_amdgcn_mfma_f32_16x16x32_bf16(pf[mt], vfp[ks][1], acc[mt][1], 0, 0, 0);
                }
            }
            #pragma unroll
            for (int ks = 0; ks < 2; ++ks) {
                bf8 pf[4];
                #pragma unroll
                for (int mt = 0; mt < 4; ++mt)
                    pf[mt] = *(const bf8*)&pbR[mt * 16 + c15][(ks + 2) * 32 + 8 * g];
                #pragma unroll
                for (int mt = 0; mt < 4; ++mt) {
                    acc[mt][0] = __builtin_amdgcn_mfma_f32_16x16x32_bf16(pf[mt], vfl[ks][0], acc[mt][0], 0, 0, 0);
                    acc[mt][1] = __builtin_amdgcn_mfma_f32_16x16x32_bf16(pf[mt], vfl[ks][1], acc[mt][1], 0, 0, 0);
                }
            }
            __builtin_amdgcn_s_setprio(0);
        } else if (i < 31) {
            // ================= PRODUCE tile j = i+1 =================
            const int j = i + 1;
            // V prefetch ks{0,1} for my consume next region (tile j)
            #pragma unroll
            for (int ks = 0; ks < 2; ++ks)
                #pragma unroll
                for (int ct = 0; ct < 2; ++ct)
                    vfp[ks][ct] = *(const bf8*)(vB + (size_t)(ct * 16 + c15) * N_
                                                + j * 128 + ks * 32 + g * 8);
            unsigned short (*pbW)[136] = Ps[(i & 1) ^ 1];
            #pragma unroll
            for (int nf = 0; nf < 2; ++nf) {
                f4 s[4];
                #pragma unroll
                for (int mi = 0; mi < 4; ++mi)
                    s[mi] = __builtin_amdgcn_mfma_f32_16x16x32_bf16(kfc[nf], qf[mi], fz, 0, 0, 0);
                #pragma unroll
                for (int mi = 0; mi < 4; ++mi) {
                    float p0 = __builtin_amdgcn_exp2f(s[mi].x);
                    float p1 = __builtin_amdgcn_exp2f(s[mi].y);
                    float p2 = __builtin_amdgcn_exp2f(s[mi].z);
                    float p3 = __builtin_amdgcn_exp2f(s[mi].w);
                    lr[mi] += (p0 + p1) + (p2 + p3);
                    uint2 pk; pk.x = pk2(p0, p1); pk.y = pk2(p2, p3);
                    *(uint2*)&pbW[mi * 16 + c15][(2 * u + nf) * 16 + 4 * g] = pk;
                }
            }
        }
        // light barrier: drain LDS ops only; global loads stay in flight
        asm volatile("s_waitcnt lgkmcnt(0)\n\ts_barrier" ::: "memory");
    }

    // l: reduce over g-groups, one 16-col partial per wave -> l_s
    #pragma unroll
    for (int mi = 0; mi < 4; ++mi) {
        lr[mi] += __shfl_xor(lr[mi], 16);
        lr[mi] += __shfl_xor(lr[mi], 32);
    }
    if (lane < 16) {
        #pragma unroll
        for (int mi = 0; mi < 4; ++mi) l_s[w][mi * 16 + lane] = lr[mi];
    }
    __syncthreads();   // all consume reads of Ps done before acc dump reuses it

    float* accs = (float*)Ps;  // 32 KB reuse for group-combine
    if (grp == 1) {
        #pragma unroll
        for (int mt = 0; mt < 4; ++mt)
            #pragma unroll
            for (int ct = 0; ct < 2; ++ct)
                *(f4*)&accs[(((u * 8 + mt * 2 + ct) * 64) + lane) * 4] = acc[mt][ct];
    }
    if (w == 0) {
        float sacc = 0.f;
        #pragma unroll
        for (int ww = 0; ww < 8; ++ww) sacc += l_s[ww][lane];
        l_tot[lane] = sacc;
    }
    __syncthreads();
    if (grp == 0) {
        const float g0 = gamma[0];
        #pragma unroll
        for (int mt = 0; mt < 4; ++mt) {
            float4 lv = *(const float4*)&l_tot[mt * 16 + 4 * g];
            float i0 = 1.f / lv.x, i1 = 1.f / lv.y, i2 = 1.f / lv.z, i3 = 1.f / lv.w;
            #pragma unroll
            for (int ct = 0; ct < 2; ++ct) {
                f4 o = *(const f4*)&accs[(((u * 8 + mt * 2 + ct) * 64) + lane) * 4];
                f4 a = acc[mt][ct];
                int c = c0 + u * 32 + ct * 16 + c15;
                size_t base = ((size_t)(b * C_ + c)) * (size_t)N_ + m0 + mt * 16 + 4 * g;
                float4 xv = *(const float4*)(x + base);
                float4 r;
                r.x = g0 * ((a.x + o.x) * i0) + xv.x;
                r.y = g0 * ((a.y + o.y) * i1) + xv.y;
                r.z = g0 * ((a.z + o.z) * i2) + xv.z;
                r.w = g0 * ((a.w + o.w) * i3) + xv.w;
                *(float4*)(out + base) = r;
            }
        }
    }
}

extern "C" void kernel_launch(void* const* d_in, const int* in_sizes, int n_in,
                              void* d_out, int out_size, void* d_ws, size_t ws_size,
                              hipStream_t stream) {
    const float* x     = (const float*)d_in[0];
    const float* Wq    = (const float*)d_in[1];
    const float* bq    = (const float*)d_in[2];
    const float* Wk    = (const float*)d_in[3];
    const float* bk    = (const float*)d_in[4];
    const float* Wv    = (const float*)d_in[5];
    const float* bv    = (const float*)d_in[6];
    const float* gamma = (const float*)d_in[7];
    float* out = (float*)d_out;

    unsigned short* qb   = (unsigned short*)d_ws;
    unsigned short* kb   = qb + (size_t)B_ * N_ * D_;
    unsigned short* vb   = kb + (size_t)B_ * N_ * D_;
    unsigned short* Wqkb = vb + (size_t)B_ * C_ * N_;
    unsigned short* Wvb  = Wqkb + 64 * C_;

    prep<<<256, 256, 0, stream>>>(Wq, Wk, Wv, Wqkb, Wvb);
    qkv<<<dim3(128, 4), 256, 0, stream>>>(x, Wqkb, Wvb, bq, bk, bv, qb, kb, vb);
    attn<<<dim3(512), 512, 0, stream>>>(qb, kb, vb, x, gamma, out);
}

// Round 8
// 226.426 us; speedup vs baseline: 1.3696x; 1.0561x over previous
//
#include <hip/hip_runtime.h>

#define B_  4
#define N_  4096   // H*W
#define C_  256
#define D_  32

typedef __attribute__((ext_vector_type(8))) short bf8;   // 8 bf16 (4 VGPRs)
typedef __attribute__((ext_vector_type(4))) float f4;    // MFMA C/D frag

__device__ __forceinline__ unsigned short bft(float f) {
    unsigned u = __builtin_bit_cast(unsigned, f);
    return (unsigned short)((u + 0x8000u) >> 16);
}
// pack two floats to bf16x2 (a->low, b->high), round-half-up, 3 VALU ops
__device__ __forceinline__ unsigned pk2(float a, float b) {
    unsigned ua = __builtin_bit_cast(unsigned, a) + 0x8000u;
    unsigned ub = __builtin_bit_cast(unsigned, b) + 0x8000u;
    return __builtin_amdgcn_perm(ub, ua, 0x07060302u);  // bytes {b3,b2,a3,a2}
}

// ---------------------------------------------------------------------------
// prep: weights -> bf16. Wqkb[64][256] = Wq rows 0-31, Wk rows 32-63.
// ---------------------------------------------------------------------------
__global__ __launch_bounds__(256) void prep(
    const float* __restrict__ Wq, const float* __restrict__ Wk,
    const float* __restrict__ Wv,
    unsigned short* __restrict__ Wqkb, unsigned short* __restrict__ Wvb)
{
    int i = blockIdx.x * 256 + threadIdx.x;
    if (i < 8192)       Wqkb[i] = bft(Wq[i]);
    else if (i < 16384) Wqkb[i] = bft(Wk[i - 8192]);
    Wvb[i] = bft(Wv[i]);
}

// ---------------------------------------------------------------------------
// qkv: MFMA projections, coalesced staging. grid(128,4), 256 thr.
// q is pre-scaled by log2(e) so attn can use raw v_exp_f32 (2^x).
// Outputs: qb,kb [B][N][32] bf16 ; vb [B][C][N] bf16.
// ---------------------------------------------------------------------------
__global__ __launch_bounds__(256) void qkv(
    const float* __restrict__ x,
    const unsigned short* __restrict__ Wqkb, const unsigned short* __restrict__ Wvb,
    const float* __restrict__ bq, const float* __restrict__ bk,
    const float* __restrict__ bv,
    unsigned short* __restrict__ qb, unsigned short* __restrict__ kb,
    unsigned short* __restrict__ vb)
{
    const int b = blockIdx.y, n0 = blockIdx.x * 32;
    const int t = threadIdx.x;
    const int lane = t & 63, w = t >> 6, c15 = lane & 15, g = lane >> 4;

    __shared__ __align__(16) unsigned short xs[32][264];

    // coalesced stage + transpose: 8 lanes cover one 128-B row segment
    {
        const int r = t >> 3, cg = t & 7;
        #pragma unroll
        for (int it = 0; it < 8; ++it) {
            int c = r + 32 * it;
            float4 v = *(const float4*)(x + ((size_t)(b * C_ + c)) * N_ + n0 + cg * 4);
            xs[cg * 4 + 0][c] = bft(v.x);
            xs[cg * 4 + 1][c] = bft(v.y);
            xs[cg * 4 + 2][c] = bft(v.z);
            xs[cg * 4 + 3][c] = bft(v.w);
        }
    }
    __syncthreads();

    f4 qkacc[2]; f4 vacc[2][4];
    const f4 fz = {0.f, 0.f, 0.f, 0.f};
    qkacc[0] = fz; qkacc[1] = fz;
    #pragma unroll
    for (int nt = 0; nt < 2; ++nt)
        #pragma unroll
        for (int ct = 0; ct < 4; ++ct) vacc[nt][ct] = fz;

    const unsigned short* wqk = Wqkb + (w * 16 + c15) * C_ + g * 8;
    const unsigned short* wv0 = Wvb + (w * 64 + c15) * C_ + g * 8;
    const unsigned short* xsp = &xs[c15][g * 8];

    #pragma unroll
    for (int ks = 0; ks < 8; ++ks) {
        bf8 xf0 = *(const bf8*)(xsp + ks * 32);
        bf8 xf1 = *(const bf8*)(xsp + 16 * 264 + ks * 32);
        bf8 af  = *(const bf8*)(wqk + ks * 32);
        qkacc[0] = __builtin_amdgcn_mfma_f32_16x16x32_bf16(af, xf0, qkacc[0], 0, 0, 0);
        qkacc[1] = __builtin_amdgcn_mfma_f32_16x16x32_bf16(af, xf1, qkacc[1], 0, 0, 0);
        #pragma unroll
        for (int ct = 0; ct < 4; ++ct) {
            bf8 bfv = *(const bf8*)(wv0 + ct * 16 * C_ + ks * 32);
            vacc[0][ct] = __builtin_amdgcn_mfma_f32_16x16x32_bf16(xf0, bfv, vacc[0][ct], 0, 0, 0);
            vacc[1][ct] = __builtin_amdgcn_mfma_f32_16x16x32_bf16(xf1, bfv, vacc[1][ct], 0, 0, 0);
        }
    }

    // epilogue q/k (q scaled by log2e for exp2-softmax)
    {
        float4 bias = (w < 2) ? *(const float4*)(bq + (w & 1) * 16 + 4 * g)
                              : *(const float4*)(bk + (w & 1) * 16 + 4 * g);
        float sc = (w < 2) ? 1.44269504f : 1.0f;
        unsigned short* base = (w < 2) ? qb : kb;
        int d0 = (w & 1) * 16 + 4 * g;
        #pragma unroll
        for (int nt = 0; nt < 2; ++nt) {
            int n = n0 + nt * 16 + c15;
            f4 a = qkacc[nt];
            uint2 pk;
            pk.x = pk2((a.x + bias.x) * sc, (a.y + bias.y) * sc);
            pk.y = pk2((a.z + bias.z) * sc, (a.w + bias.w) * sc);
            *(uint2*)(base + ((size_t)(b * N_ + n)) * D_ + d0) = pk;
        }
    }
    // epilogue v
    #pragma unroll
    for (int ct = 0; ct < 4; ++ct) {
        int cout = w * 64 + ct * 16 + c15;
        float bvv = bv[cout];
        #pragma unroll
        for (int nt = 0; nt < 2; ++nt) {
            f4 a = vacc[nt][ct];
            uint2 pk;
            pk.x = pk2(a.x + bvv, a.y + bvv);
            pk.y = pk2(a.z + bvv, a.w + bvv);
            *(uint2*)(vb + ((size_t)(b * C_ + cout)) * (size_t)N_ + n0 + nt * 16 + 4 * g) = pk;
        }
    }
}

// ---------------------------------------------------------------------------
// attn v9: small independent barrier groups. Block = 32 m x 128 c-half,
// 4 waves (256 thr); grid 1024 = 128mb x 4b x 2ch -> 4 blocks/CU = FOUR
// independent barrier groups (v2/v5 had two 8-wave groups whose convoy left
// every pipe at ~25%). Region internals = proven v5 shape: fused
// consume(i)+produce(i+1), ONE lgkmcnt-only barrier per region, region-ahead
// K/V prefetch, every buffer singly-named & role-static (v8's divergent
// role-swap spilled 225MB to scratch -- avoided entirely here).
// produce: wave w owns n-frags {2w,2w+1} (4 QK MFMA, 16 exp2, 4 b64 writes).
// consume: wave w owns c-range w*32, ALL k (16 PV MFMA) -> no ksh combine,
// direct epilogue. P LDS [32][136] (272-B rows): b128 reads at bank floor,
// b64 writes 2x floor (free, m136). bid&7=(b,ch) XCD-pins V slices; V L2
// traffic ~2.6 TB/s/XCD < 4.3 ceiling. setprio(1) wraps PV clusters (T5:
// 4 groups at drifted phases = role diversity to arbitrate).
// ---------------------------------------------------------------------------
__global__ __launch_bounds__(256, 4) void attn(
    const unsigned short* __restrict__ qb, const unsigned short* __restrict__ kb,
    const unsigned short* __restrict__ vb, const float* __restrict__ x,
    const float* __restrict__ gamma, float* __restrict__ out)
{
    const int bid = blockIdx.x;
    const int combo = bid & 7, mb = bid >> 3;
    const int b = combo >> 1, c0 = (combo & 1) * 128, m0 = mb * 32;
    const int t = threadIdx.x;
    const int lane = t & 63, w = t >> 6, c15 = lane & 15, g = lane >> 4;

    __shared__ __align__(16) unsigned short Ps[2][32][136];  // 272-B rows
    __shared__ float l_s[4][32];
    __shared__ __align__(16) float l_tot[32];

    const f4 fz = {0.f, 0.f, 0.f, 0.f};

    bf8 qf[2];
    #pragma unroll
    for (int mi = 0; mi < 2; ++mi)
        qf[mi] = *(const bf8*)(qb + ((size_t)(b * N_ + m0 + mi * 16 + c15)) * D_ + g * 8);

    f4 acc[2][2];
    #pragma unroll
    for (int mt = 0; mt < 2; ++mt)
        #pragma unroll
        for (int ct = 0; ct < 2; ++ct) acc[mt][ct] = fz;
    float lr[2] = {0.f, 0.f};

    const unsigned short* kB = kb + (size_t)b * N_ * D_;
    const unsigned short* vB = vb + ((size_t)(b * C_ + c0 + w * 32)) * (size_t)N_;

    bf8 kcur[2];     // K frags for next tile's produce (region-ahead)
    bf8 vfp[2][2];   // V ks{0,1} of current consume tile (region-ahead)

    // ---- prologue: produce tile 0; stage V(0,ks01), K(1) ----
    {
        bf8 kf0[2];
        #pragma unroll
        for (int nf = 0; nf < 2; ++nf)
            kf0[nf] = *(const bf8*)(kB + (size_t)((2 * w + nf) * 16 + c15) * D_ + g * 8);
        #pragma unroll
        for (int ks = 0; ks < 2; ++ks)
            #pragma unroll
            for (int ct = 0; ct < 2; ++ct)
                vfp[ks][ct] = *(const bf8*)(vB + (size_t)(ct * 16 + c15) * N_ + ks * 32 + g * 8);
        #pragma unroll
        for (int nf = 0; nf < 2; ++nf)
            kcur[nf] = *(const bf8*)(kB + (size_t)(128 + (2 * w + nf) * 16 + c15) * D_ + g * 8);
        #pragma unroll
        for (int mi = 0; mi < 2; ++mi)
            #pragma unroll
            for (int nf = 0; nf < 2; ++nf) {
                f4 s = __builtin_amdgcn_mfma_f32_16x16x32_bf16(kf0[nf], qf[mi], fz, 0, 0, 0);
                float p0 = __builtin_amdgcn_exp2f(s.x);
                float p1 = __builtin_amdgcn_exp2f(s.y);
                float p2 = __builtin_amdgcn_exp2f(s.z);
                float p3 = __builtin_amdgcn_exp2f(s.w);
                lr[mi] += (p0 + p1) + (p2 + p3);
                uint2 pk; pk.x = pk2(p0, p1); pk.y = pk2(p2, p3);
                *(uint2*)&Ps[0][mi * 16 + c15][(2 * w + nf) * 16 + 4 * g] = pk;
            }
        asm volatile("s_waitcnt lgkmcnt(0)\n\ts_barrier" ::: "memory");
    }

    // ---- main: region i = consume(i) + produce(i+1) ----
    for (int i = 0; i < 31; ++i) {
        const int j0 = i << 7;
        const unsigned short (*pbR)[136] = Ps[i & 1];
        unsigned short (*pbW)[136] = Ps[(i & 1) ^ 1];
        // V ks{2,3} of tile i (used after first PV half, ~300+ cyc of cover)
        bf8 vfl[2][2];
        #pragma unroll
        for (int ks = 0; ks < 2; ++ks)
            #pragma unroll
            for (int ct = 0; ct < 2; ++ct)
                vfl[ks][ct] = *(const bf8*)(vB + (size_t)(ct * 16 + c15) * N_
                                            + j0 + (ks + 2) * 32 + g * 8);
        // P reads ks{0,1}
        bf8 pf0[2][2];
        #pragma unroll
        for (int mt = 0; mt < 2; ++mt)
            #pragma unroll
            for (int ks = 0; ks < 2; ++ks)
                pf0[mt][ks] = *(const bf8*)&pbR[mt * 16 + c15][ks * 32 + 8 * g];
        // QK MFMAs for tile i+1 (kcur prefetched last region)
        f4 s[2][2];
        #pragma unroll
        for (int mi = 0; mi < 2; ++mi)
            #pragma unroll
            for (int nf = 0; nf < 2; ++nf)
                s[mi][nf] = __builtin_amdgcn_mfma_f32_16x16x32_bf16(kcur[nf], qf[mi], fz, 0, 0, 0);
        // PV ks{0,1}
        __builtin_amdgcn_s_setprio(1);
        #pragma unroll
        for (int mt = 0; mt < 2; ++mt)
            #pragma unroll
            for (int ks = 0; ks < 2; ++ks)
                #pragma unroll
                for (int ct = 0; ct < 2; ++ct)
                    acc[mt][ct] = __builtin_amdgcn_mfma_f32_16x16x32_bf16(pf0[mt][ks], vfp[ks][ct], acc[mt][ct], 0, 0, 0);
        __builtin_amdgcn_s_setprio(0);
        // exp2 / pack / P-write for tile i+1
        #pragma unroll
        for (int mi = 0; mi < 2; ++mi)
            #pragma unroll
            for (int nf = 0; nf < 2; ++nf) {
                float p0 = __builtin_amdgcn_exp2f(s[mi][nf].x);
                float p1 = __builtin_amdgcn_exp2f(s[mi][nf].y);
                float p2 = __builtin_amdgcn_exp2f(s[mi][nf].z);
                float p3 = __builtin_amdgcn_exp2f(s[mi][nf].w);
                lr[mi] += (p0 + p1) + (p2 + p3);
                uint2 pk; pk.x = pk2(p0, p1); pk.y = pk2(p2, p3);
                *(uint2*)&pbW[mi * 16 + c15][(2 * w + nf) * 16 + 4 * g] = pk;
            }
        // prefetch: K for tile i+2, V ks{0,1} for tile i+1
        if (i < 30) {
            #pragma unroll
            for (int nf = 0; nf < 2; ++nf)
                kcur[nf] = *(const bf8*)(kB + (size_t)((i + 2) * 128 + (2 * w + nf) * 16 + c15) * D_ + g * 8);
        }
        #pragma unroll
        for (int ks = 0; ks < 2; ++ks)
            #pragma unroll
            for (int ct = 0; ct < 2; ++ct)
                vfp[ks][ct] = *(const bf8*)(vB + (size_t)(ct * 16 + c15) * N_
                                            + j0 + 128 + ks * 32 + g * 8);
        // P reads ks{2,3} + PV
        bf8 pf1[2][2];
        #pragma unroll
        for (int mt = 0; mt < 2; ++mt)
            #pragma unroll
            for (int ks = 0; ks < 2; ++ks)
                pf1[mt][ks] = *(const bf8*)&pbR[mt * 16 + c15][(ks + 2) * 32 + 8 * g];
        __builtin_amdgcn_s_setprio(1);
        #pragma unroll
        for (int mt = 0; mt < 2; ++mt)
            #pragma unroll
            for (int ks = 0; ks < 2; ++ks)
                #pragma unroll
                for (int ct = 0; ct < 2; ++ct)
                    acc[mt][ct] = __builtin_amdgcn_mfma_f32_16x16x32_bf16(pf1[mt][ks], vfl[ks][ct], acc[mt][ct], 0, 0, 0);
        __builtin_amdgcn_s_setprio(0);
        // light barrier: drain LDS only; global loads stay in flight
        asm volatile("s_waitcnt lgkmcnt(0)\n\ts_barrier" ::: "memory");
    }

    // ---- final consume: tile 31 (in Ps[1]) ----
    {
        const int j0 = 31 * 128;
        const unsigned short (*pbR)[136] = Ps[1];
        bf8 vfl[2][2];
        #pragma unroll
        for (int ks = 0; ks < 2; ++ks)
            #pragma unroll
            for (int ct = 0; ct < 2; ++ct)
                vfl[ks][ct] = *(const bf8*)(vB + (size_t)(ct * 16 + c15) * N_
                                            + j0 + (ks + 2) * 32 + g * 8);
        #pragma unroll
        for (int mt = 0; mt < 2; ++mt)
            #pragma unroll
            for (int ks = 0; ks < 2; ++ks) {
                bf8 pf = *(const bf8*)&pbR[mt * 16 + c15][ks * 32 + 8 * g];
                #pragma unroll
                for (int ct = 0; ct < 2; ++ct)
                    acc[mt][ct] = __builtin_amdgcn_mfma_f32_16x16x32_bf16(pf, vfp[ks][ct], acc[mt][ct], 0, 0, 0);
            }
        #pragma unroll
        for (int mt = 0; mt < 2; ++mt)
            #pragma unroll
            for (int ks = 0; ks < 2; ++ks) {
                bf8 pf = *(const bf8*)&pbR[mt * 16 + c15][(ks + 2) * 32 + 8 * g];
                #pragma unroll
                for (int ct = 0; ct < 2; ++ct)
                    acc[mt][ct] = __builtin_amdgcn_mfma_f32_16x16x32_bf16(pf, vfl[ks][ct], acc[mt][ct], 0, 0, 0);
            }
    }

    // l: reduce over g-groups, per-wave partial -> l_s, then sum 4 waves
    #pragma unroll
    for (int mi = 0; mi < 2; ++mi) {
        lr[mi] += __shfl_xor(lr[mi], 16);
        lr[mi] += __shfl_xor(lr[mi], 32);
    }
    if (lane < 16) {
        l_s[w][lane] = lr[0];
        l_s[w][16 + lane] = lr[1];
    }
    __syncthreads();
    if (t < 32) {
        float sacc = 0.f;
        #pragma unroll
        for (int ww = 0; ww < 4; ++ww) sacc += l_s[ww][t];
        l_tot[t] = sacc;
    }
    __syncthreads();

    // epilogue: wave w writes its 32m x 32c tile directly (owns all k)
    {
        const float g0 = gamma[0];
        #pragma unroll
        for (int mt = 0; mt < 2; ++mt) {
            float4 lv = *(const float4*)&l_tot[mt * 16 + 4 * g];
            float i0 = 1.f / lv.x, i1 = 1.f / lv.y, i2 = 1.f / lv.z, i3 = 1.f / lv.w;
            #pragma unroll
            for (int ct = 0; ct < 2; ++ct) {
                f4 a = acc[mt][ct];
                int c = c0 + w * 32 + ct * 16 + c15;
                size_t base = ((size_t)(b * C_ + c)) * (size_t)N_ + m0 + mt * 16 + 4 * g;
                float4 xv = *(const float4*)(x + base);
                float4 r;
                r.x = g0 * (a.x * i0) + xv.x;
                r.y = g0 * (a.y * i1) + xv.y;
                r.z = g0 * (a.z * i2) + xv.z;
                r.w = g0 * (a.w * i3) + xv.w;
                *(float4*)(out + base) = r;
            }
        }
    }
}

extern "C" void kernel_launch(void* const* d_in, const int* in_sizes, int n_in,
                              void* d_out, int out_size, void* d_ws, size_t ws_size,
                              hipStream_t stream) {
    const float* x     = (const float*)d_in[0];
    const float* Wq    = (const float*)d_in[1];
    const float* bq    = (const float*)d_in[2];
    const float* Wk    = (const float*)d_in[3];
    const float* bk    = (const float*)d_in[4];
    const float* Wv    = (const float*)d_in[5];
    const float* bv    = (const float*)d_in[6];
    const float* gamma = (const float*)d_in[7];
    float* out = (float*)d_out;

    unsigned short* qb   = (unsigned short*)d_ws;
    unsigned short* kb   = qb + (size_t)B_ * N_ * D_;
    unsigned short* vb   = kb + (size_t)B_ * N_ * D_;
    unsigned short* Wqkb = vb + (size_t)B_ * C_ * N_;
    unsigned short* Wvb  = Wqkb + 64 * C_;

    prep<<<256, 256, 0, stream>>>(Wq, Wk, Wv, Wqkb, Wvb);
    qkv<<<dim3(128, 4), 256, 0, stream>>>(x, Wqkb, Wvb, bq, bk, bv, qb, kb, vb);
    attn<<<dim3(1024), 256, 0, stream>>>(qb, kb, vb, x, gamma, out);
}

// Round 9
// 175.318 us; speedup vs baseline: 1.7689x; 1.2915x over previous
//
#include <hip/hip_runtime.h>

#define B_  4
#define N_  4096   // H*W
#define C_  256
#define D_  32

typedef __attribute__((ext_vector_type(8))) short bf8;   // 8 bf16 (4 VGPRs)
typedef __attribute__((ext_vector_type(4))) float f4;    // MFMA C/D frag

__device__ __forceinline__ unsigned short bft(float f) {
    unsigned u = __builtin_bit_cast(unsigned, f);
    return (unsigned short)((u + 0x8000u) >> 16);
}
// pack two floats to bf16x2 (a->low, b->high), round-half-up, 3 VALU ops
__device__ __forceinline__ unsigned pk2(float a, float b) {
    unsigned ua = __builtin_bit_cast(unsigned, a) + 0x8000u;
    unsigned ub = __builtin_bit_cast(unsigned, b) + 0x8000u;
    return __builtin_amdgcn_perm(ub, ua, 0x07060302u);  // bytes {b3,b2,a3,a2}
}

// ---------------------------------------------------------------------------
// prep: weights -> bf16. Wqkb[64][256] = Wq rows 0-31, Wk rows 32-63.
// ---------------------------------------------------------------------------
__global__ __launch_bounds__(256) void prep(
    const float* __restrict__ Wq, const float* __restrict__ Wk,
    const float* __restrict__ Wv,
    unsigned short* __restrict__ Wqkb, unsigned short* __restrict__ Wvb)
{
    int i = blockIdx.x * 256 + threadIdx.x;
    if (i < 8192)       Wqkb[i] = bft(Wq[i]);
    else if (i < 16384) Wqkb[i] = bft(Wk[i - 8192]);
    Wvb[i] = bft(Wv[i]);
}

// ---------------------------------------------------------------------------
// qkv: MFMA projections, coalesced staging. grid(128,4), 256 thr.
// q is pre-scaled by log2(e) so attn can use raw v_exp_f32 (2^x).
// Outputs: qb,kb [B][N][32] bf16 ; vb [B][C][N] bf16.
// ---------------------------------------------------------------------------
__global__ __launch_bounds__(256) void qkv(
    const float* __restrict__ x,
    const unsigned short* __restrict__ Wqkb, const unsigned short* __restrict__ Wvb,
    const float* __restrict__ bq, const float* __restrict__ bk,
    const float* __restrict__ bv,
    unsigned short* __restrict__ qb, unsigned short* __restrict__ kb,
    unsigned short* __restrict__ vb)
{
    const int b = blockIdx.y, n0 = blockIdx.x * 32;
    const int t = threadIdx.x;
    const int lane = t & 63, w = t >> 6, c15 = lane & 15, g = lane >> 4;

    __shared__ __align__(16) unsigned short xs[32][264];

    // coalesced stage + transpose: 8 lanes cover one 128-B row segment
    {
        const int r = t >> 3, cg = t & 7;
        #pragma unroll
        for (int it = 0; it < 8; ++it) {
            int c = r + 32 * it;
            float4 v = *(const float4*)(x + ((size_t)(b * C_ + c)) * N_ + n0 + cg * 4);
            xs[cg * 4 + 0][c] = bft(v.x);
            xs[cg * 4 + 1][c] = bft(v.y);
            xs[cg * 4 + 2][c] = bft(v.z);
            xs[cg * 4 + 3][c] = bft(v.w);
        }
    }
    __syncthreads();

    f4 qkacc[2]; f4 vacc[2][4];
    const f4 fz = {0.f, 0.f, 0.f, 0.f};
    qkacc[0] = fz; qkacc[1] = fz;
    #pragma unroll
    for (int nt = 0; nt < 2; ++nt)
        #pragma unroll
        for (int ct = 0; ct < 4; ++ct) vacc[nt][ct] = fz;

    const unsigned short* wqk = Wqkb + (w * 16 + c15) * C_ + g * 8;
    const unsigned short* wv0 = Wvb + (w * 64 + c15) * C_ + g * 8;
    const unsigned short* xsp = &xs[c15][g * 8];

    #pragma unroll
    for (int ks = 0; ks < 8; ++ks) {
        bf8 xf0 = *(const bf8*)(xsp + ks * 32);
        bf8 xf1 = *(const bf8*)(xsp + 16 * 264 + ks * 32);
        bf8 af  = *(const bf8*)(wqk + ks * 32);
        qkacc[0] = __builtin_amdgcn_mfma_f32_16x16x32_bf16(af, xf0, qkacc[0], 0, 0, 0);
        qkacc[1] = __builtin_amdgcn_mfma_f32_16x16x32_bf16(af, xf1, qkacc[1], 0, 0, 0);
        #pragma unroll
        for (int ct = 0; ct < 4; ++ct) {
            bf8 bfv = *(const bf8*)(wv0 + ct * 16 * C_ + ks * 32);
            vacc[0][ct] = __builtin_amdgcn_mfma_f32_16x16x32_bf16(xf0, bfv, vacc[0][ct], 0, 0, 0);
            vacc[1][ct] = __builtin_amdgcn_mfma_f32_16x16x32_bf16(xf1, bfv, vacc[1][ct], 0, 0, 0);
        }
    }

    // epilogue q/k (q scaled by log2e for exp2-softmax)
    {
        float4 bias = (w < 2) ? *(const float4*)(bq + (w & 1) * 16 + 4 * g)
                              : *(const float4*)(bk + (w & 1) * 16 + 4 * g);
        float sc = (w < 2) ? 1.44269504f : 1.0f;
        unsigned short* base = (w < 2) ? qb : kb;
        int d0 = (w & 1) * 16 + 4 * g;
        #pragma unroll
        for (int nt = 0; nt < 2; ++nt) {
            int n = n0 + nt * 16 + c15;
            f4 a = qkacc[nt];
            uint2 pk;
            pk.x = pk2((a.x + bias.x) * sc, (a.y + bias.y) * sc);
            pk.y = pk2((a.z + bias.z) * sc, (a.w + bias.w) * sc);
            *(uint2*)(base + ((size_t)(b * N_ + n)) * D_ + d0) = pk;
        }
    }
    // epilogue v
    #pragma unroll
    for (int ct = 0; ct < 4; ++ct) {
        int cout = w * 64 + ct * 16 + c15;
        float bvv = bv[cout];
        #pragma unroll
        for (int nt = 0; nt < 2; ++nt) {
            f4 a = vacc[nt][ct];
            uint2 pk;
            pk.x = pk2(a.x + bvv, a.y + bvv);
            pk.y = pk2(a.z + bvv, a.w + bvv);
            *(uint2*)(vb + ((size_t)(b * C_ + cout)) * (size_t)N_ + n0 + nt * 16 + 4 * g) = pk;
        }
    }
}

// ---------------------------------------------------------------------------
// attn v10: the v5 champion (M=64, c-half, 8 waves, grid 512, 2 blocks/CU,
// fused consume(i)+produce(i+1) regions, light lgkmcnt barrier) with the
// K-tile doubled to KT=256 -> 16 regions instead of 32. v5's region wall
// (6150 cyc) carries ~1.2-1.6k cyc of barrier-convoy slack; halving the
// region count halves that overhead while all work terms stay identical.
// produce: wave w owns n-frags {2w, 2w+1} of the next 256-tile
//          (8 QK MFMA, 32 exp2, 16 pk2, 8 b64 writes).
// consume: wave (cq=w&3, ksh=w>>2): c-range cq*32, k-half ksh*128 as 4
//          ks-chunks of 32 (16 P b128 reads, 32 PV MFMA).
// P LDS [2][64][264] (528-B padded rows): b128 reads 2-way aliased (free,
// m136), b64 writes 4 words/bank (floor). ksh-combine + epilogue = v5.
// Per-mi scoping keeps register liveness near v5's 64 VGPR.
// ---------------------------------------------------------------------------
__global__ __launch_bounds__(512, 4) void attn(
    const unsigned short* __restrict__ qb, const unsigned short* __restrict__ kb,
    const unsigned short* __restrict__ vb, const float* __restrict__ x,
    const float* __restrict__ gamma, float* __restrict__ out)
{
    const int bid = blockIdx.x;
    const int combo = bid & 7, mb = bid >> 3;
    const int b = combo >> 1, c0 = (combo & 1) * 128, m0 = mb * 64;
    const int t = threadIdx.x;
    const int lane = t & 63, w = t >> 6, c15 = lane & 15, g = lane >> 4;
    const int cq = w & 3, ksh = w >> 2;          // consume role

    __shared__ __align__(16) unsigned short Ps[2][64][264];  // 528-B rows
    __shared__ float l_s[8][64];
    __shared__ __align__(16) float l_tot[64];

    const f4 fz = {0.f, 0.f, 0.f, 0.f};

    bf8 qf[4];
    #pragma unroll
    for (int mi = 0; mi < 4; ++mi)
        qf[mi] = *(const bf8*)(qb + ((size_t)(b * N_ + m0 + mi * 16 + c15)) * D_ + g * 8);

    f4 acc[4][2];
    #pragma unroll
    for (int mt = 0; mt < 4; ++mt)
        #pragma unroll
        for (int ct = 0; ct < 2; ++ct) acc[mt][ct] = fz;
    float lr[4] = {0.f, 0.f, 0.f, 0.f};

    const unsigned short* kB = kb + (size_t)b * N_ * D_;
    const unsigned short* vB = vb + ((size_t)(b * C_ + c0 + cq * 32)) * (size_t)N_;

    bf8 kcur[2];     // K frags (my 2 n-frags) of the NEXT produce tile
    bf8 vfp[2][2];   // V ks{0,1} of the current consume tile

    // ---- prologue: produce tile 0; prefetch V(0,ks01), K(1) ----
    {
        #pragma unroll
        for (int nf = 0; nf < 2; ++nf) {
            bf8 kf0 = *(const bf8*)(kB + (size_t)((2 * w + nf) * 16 + c15) * D_ + g * 8);
            #pragma unroll
            for (int mi = 0; mi < 4; ++mi) {
                f4 s = __builtin_amdgcn_mfma_f32_16x16x32_bf16(kf0, qf[mi], fz, 0, 0, 0);
                float p0 = __builtin_amdgcn_exp2f(s.x);
                float p1 = __builtin_amdgcn_exp2f(s.y);
                float p2 = __builtin_amdgcn_exp2f(s.z);
                float p3 = __builtin_amdgcn_exp2f(s.w);
                lr[mi] += (p0 + p1) + (p2 + p3);
                uint2 pk; pk.x = pk2(p0, p1); pk.y = pk2(p2, p3);
                *(uint2*)&Ps[0][mi * 16 + c15][(2 * w + nf) * 16 + 4 * g] = pk;
            }
        }
        #pragma unroll
        for (int ks = 0; ks < 2; ++ks)
            #pragma unroll
            for (int ct = 0; ct < 2; ++ct)
                vfp[ks][ct] = *(const bf8*)(vB + (size_t)(ct * 16 + c15) * N_
                                            + ksh * 128 + ks * 32 + g * 8);
        #pragma unroll
        for (int nf = 0; nf < 2; ++nf)
            kcur[nf] = *(const bf8*)(kB + (size_t)(256 + (2 * w + nf) * 16 + c15) * D_ + g * 8);
        asm volatile("s_waitcnt lgkmcnt(0)\n\ts_barrier" ::: "memory");
    }

    // ---- main: region i = consume(tile i) + produce(tile i+1), i=0..14 ----
    for (int i = 0; i < 15; ++i) {
        const int jb = i << 8;
        const unsigned short (*pbR)[264] = Ps[i & 1];
        unsigned short (*pbW)[264] = Ps[(i & 1) ^ 1];
        // V ks{2,3} of tile i (used in the second PV cluster, ~half-region away)
        bf8 vfl[2][2];
        #pragma unroll
        for (int ks = 0; ks < 2; ++ks)
            #pragma unroll
            for (int ct = 0; ct < 2; ++ct)
                vfl[ks][ct] = *(const bf8*)(vB + (size_t)(ct * 16 + c15) * N_
                                            + jb + ksh * 128 + (ks + 2) * 32 + g * 8);
        // interleave: per m-frag, PV ks{0,1} (matrix) + QK/exp/pack (trans/VALU/LDS)
        #pragma unroll
        for (int mi = 0; mi < 4; ++mi) {
            bf8 pfa = *(const bf8*)&pbR[mi * 16 + c15][ksh * 128 + 8 * g];
            bf8 pfb = *(const bf8*)&pbR[mi * 16 + c15][ksh * 128 + 32 + 8 * g];
            f4 s0 = __builtin_amdgcn_mfma_f32_16x16x32_bf16(kcur[0], qf[mi], fz, 0, 0, 0);
            f4 s1 = __builtin_amdgcn_mfma_f32_16x16x32_bf16(kcur[1], qf[mi], fz, 0, 0, 0);
            acc[mi][0] = __builtin_amdgcn_mfma_f32_16x16x32_bf16(pfa, vfp[0][0], acc[mi][0], 0, 0, 0);
            acc[mi][1] = __builtin_amdgcn_mfma_f32_16x16x32_bf16(pfa, vfp[0][1], acc[mi][1], 0, 0, 0);
            acc[mi][0] = __builtin_amdgcn_mfma_f32_16x16x32_bf16(pfb, vfp[1][0], acc[mi][0], 0, 0, 0);
            acc[mi][1] = __builtin_amdgcn_mfma_f32_16x16x32_bf16(pfb, vfp[1][1], acc[mi][1], 0, 0, 0);
            {
                float p0 = __builtin_amdgcn_exp2f(s0.x);
                float p1 = __builtin_amdgcn_exp2f(s0.y);
                float p2 = __builtin_amdgcn_exp2f(s0.z);
                float p3 = __builtin_amdgcn_exp2f(s0.w);
                lr[mi] += (p0 + p1) + (p2 + p3);
                uint2 pk; pk.x = pk2(p0, p1); pk.y = pk2(p2, p3);
                *(uint2*)&pbW[mi * 16 + c15][(2 * w + 0) * 16 + 4 * g] = pk;
            }
            {
                float p0 = __builtin_amdgcn_exp2f(s1.x);
                float p1 = __builtin_amdgcn_exp2f(s1.y);
                float p2 = __builtin_amdgcn_exp2f(s1.z);
                float p3 = __builtin_amdgcn_exp2f(s1.w);
                lr[mi] += (p0 + p1) + (p2 + p3);
                uint2 pk; pk.x = pk2(p0, p1); pk.y = pk2(p2, p3);
                *(uint2*)&pbW[mi * 16 + c15][(2 * w + 1) * 16 + 4 * g] = pk;
            }
        }
        // prefetch: K for tile i+2 (last produce is tile 15 <- loaded at i=13),
        // V ks{0,1} for tile i+1 (vfp's last use was above)
        if (i < 14) {
            #pragma unroll
            for (int nf = 0; nf < 2; ++nf)
                kcur[nf] = *(const bf8*)(kB + (size_t)((i + 2) * 256 + (2 * w + nf) * 16 + c15) * D_ + g * 8);
        }
        #pragma unroll
        for (int ks = 0; ks < 2; ++ks)
            #pragma unroll
            for (int ct = 0; ct < 2; ++ct)
                vfp[ks][ct] = *(const bf8*)(vB + (size_t)(ct * 16 + c15) * N_
                                            + jb + 256 + ksh * 128 + ks * 32 + g * 8);
        // PV ks{2,3}
        #pragma unroll
        for (int mi = 0; mi < 4; ++mi) {
            bf8 pfa = *(const bf8*)&pbR[mi * 16 + c15][ksh * 128 + 64 + 8 * g];
            bf8 pfb = *(const bf8*)&pbR[mi * 16 + c15][ksh * 128 + 96 + 8 * g];
            acc[mi][0] = __builtin_amdgcn_mfma_f32_16x16x32_bf16(pfa, vfl[0][0], acc[mi][0], 0, 0, 0);
            acc[mi][1] = __builtin_amdgcn_mfma_f32_16x16x32_bf16(pfa, vfl[0][1], acc[mi][1], 0, 0, 0);
            acc[mi][0] = __builtin_amdgcn_mfma_f32_16x16x32_bf16(pfb, vfl[1][0], acc[mi][0], 0, 0, 0);
            acc[mi][1] = __builtin_amdgcn_mfma_f32_16x16x32_bf16(pfb, vfl[1][1], acc[mi][1], 0, 0, 0);
        }
        // light barrier: drain LDS only; global loads stay in flight
        asm volatile("s_waitcnt lgkmcnt(0)\n\ts_barrier" ::: "memory");
    }

    // ---- final consume: tile 15 (written by region 14 into Ps[1]) ----
    {
        const int jb = 15 << 8;
        const unsigned short (*pbR)[264] = Ps[1];
        bf8 vfl[2][2];
        #pragma unroll
        for (int ks = 0; ks < 2; ++ks)
            #pragma unroll
            for (int ct = 0; ct < 2; ++ct)
                vfl[ks][ct] = *(const bf8*)(vB + (size_t)(ct * 16 + c15) * N_
                                            + jb + ksh * 128 + (ks + 2) * 32 + g * 8);
        #pragma unroll
        for (int mi = 0; mi < 4; ++mi) {
            bf8 pfa = *(const bf8*)&pbR[mi * 16 + c15][ksh * 128 + 8 * g];
            bf8 pfb = *(const bf8*)&pbR[mi * 16 + c15][ksh * 128 + 32 + 8 * g];
            acc[mi][0] = __builtin_amdgcn_mfma_f32_16x16x32_bf16(pfa, vfp[0][0], acc[mi][0], 0, 0, 0);
            acc[mi][1] = __builtin_amdgcn_mfma_f32_16x16x32_bf16(pfa, vfp[0][1], acc[mi][1], 0, 0, 0);
            acc[mi][0] = __builtin_amdgcn_mfma_f32_16x16x32_bf16(pfb, vfp[1][0], acc[mi][0], 0, 0, 0);
            acc[mi][1] = __builtin_amdgcn_mfma_f32_16x16x32_bf16(pfb, vfp[1][1], acc[mi][1], 0, 0, 0);
        }
        #pragma unroll
        for (int mi = 0; mi < 4; ++mi) {
            bf8 pfa = *(const bf8*)&pbR[mi * 16 + c15][ksh * 128 + 64 + 8 * g];
            bf8 pfb = *(const bf8*)&pbR[mi * 16 + c15][ksh * 128 + 96 + 8 * g];
            acc[mi][0] = __builtin_amdgcn_mfma_f32_16x16x32_bf16(pfa, vfl[0][0], acc[mi][0], 0, 0, 0);
            acc[mi][1] = __builtin_amdgcn_mfma_f32_16x16x32_bf16(pfa, vfl[0][1], acc[mi][1], 0, 0, 0);
            acc[mi][0] = __builtin_amdgcn_mfma_f32_16x16x32_bf16(pfb, vfl[1][0], acc[mi][0], 0, 0, 0);
            acc[mi][1] = __builtin_amdgcn_mfma_f32_16x16x32_bf16(pfb, vfl[1][1], acc[mi][1], 0, 0, 0);
        }
    }

    // l: reduce over g-groups, one 16-col partial per wave -> l_s
    #pragma unroll
    for (int mi = 0; mi < 4; ++mi) {
        lr[mi] += __shfl_xor(lr[mi], 16);
        lr[mi] += __shfl_xor(lr[mi], 32);
    }
    if (lane < 16) {
        #pragma unroll
        for (int mi = 0; mi < 4; ++mi) l_s[w][mi * 16 + lane] = lr[mi];
    }
    __syncthreads();   // all consume reads of Ps done before acc dump reuses it

    float* accs = (float*)Ps;  // 32 KB reuse for ksh-combine
    if (ksh == 1) {
        #pragma unroll
        for (int mt = 0; mt < 4; ++mt)
            #pragma unroll
            for (int ct = 0; ct < 2; ++ct)
                *(f4*)&accs[(((cq * 8 + mt * 2 + ct) * 64) + lane) * 4] = acc[mt][ct];
    }
    if (w == 0) {
        float sacc = 0.f;
        #pragma unroll
        for (int ww = 0; ww < 8; ++ww) sacc += l_s[ww][lane];
        l_tot[lane] = sacc;
    }
    __syncthreads();
    if (ksh == 0) {
        const float g0 = gamma[0];
        #pragma unroll
        for (int mt = 0; mt < 4; ++mt) {
            float4 lv = *(const float4*)&l_tot[mt * 16 + 4 * g];
            float i0 = 1.f / lv.x, i1 = 1.f / lv.y, i2 = 1.f / lv.z, i3 = 1.f / lv.w;
            #pragma unroll
            for (int ct = 0; ct < 2; ++ct) {
                f4 o = *(const f4*)&accs[(((cq * 8 + mt * 2 + ct) * 64) + lane) * 4];
                f4 a = acc[mt][ct];
                int c = c0 + cq * 32 + ct * 16 + c15;
                size_t base = ((size_t)(b * C_ + c)) * (size_t)N_ + m0 + mt * 16 + 4 * g;
                float4 xv = *(const float4*)(x + base);
                float4 r;
                r.x = g0 * ((a.x + o.x) * i0) + xv.x;
                r.y = g0 * ((a.y + o.y) * i1) + xv.y;
                r.z = g0 * ((a.z + o.z) * i2) + xv.z;
                r.w = g0 * ((a.w + o.w) * i3) + xv.w;
                *(float4*)(out + base) = r;
            }
        }
    }
}

extern "C" void kernel_launch(void* const* d_in, const int* in_sizes, int n_in,
                              void* d_out, int out_size, void* d_ws, size_t ws_size,
                              hipStream_t stream) {
    const float* x     = (const float*)d_in[0];
    const float* Wq    = (const float*)d_in[1];
    const float* bq    = (const float*)d_in[2];
    const float* Wk    = (const float*)d_in[3];
    const float* bk    = (const float*)d_in[4];
    const float* Wv    = (const float*)d_in[5];
    const float* bv    = (const float*)d_in[6];
    const float* gamma = (const float*)d_in[7];
    float* out = (float*)d_out;

    unsigned short* qb   = (unsigned short*)d_ws;
    unsigned short* kb   = qb + (size_t)B_ * N_ * D_;
    unsigned short* vb   = kb + (size_t)B_ * N_ * D_;
    unsigned short* Wqkb = vb + (size_t)B_ * C_ * N_;
    unsigned short* Wvb  = Wqkb + 64 * C_;

    prep<<<256, 256, 0, stream>>>(Wq, Wk, Wv, Wqkb, Wvb);
    qkv<<<dim3(128, 4), 256, 0, stream>>>(x, Wqkb, Wvb, bq, bk, bv, qb, kb, vb);
    attn<<<dim3(512), 512, 0, stream>>>(qb, kb, vb, x, gamma, out);
}